// Round 9
// baseline (271.842 us; speedup 1.0000x reference)
//
#include <hip/hip_runtime.h>

typedef __attribute__((ext_vector_type(8))) __bf16 bf16x8;
typedef __attribute__((ext_vector_type(8))) unsigned short u16x8;
typedef __attribute__((ext_vector_type(4))) float f32x4;

#define NEGV (-1e30f)

// ---------------------------------------------------------------------------
// Workspace layout (bytes):
//  Bh  : [1152][1024] bf16  @ 0          (2,359,296)
//  Bl  : [1152][1024] bf16  @ 2359296    (2,359,296)
//  Yh  : [8192][1024] bf16  @ 4718592    (16,777,216)  h_last * node_mask
//  LR  : [48][8192]  f32    @ 21495808   (1,572,864)   left/right, c = s*24+t*8+h
//  Vt  : [8][16][128][512] bf16 @ 23068672 (16,777,216) transposed h_last
//  adjB: [16][512][512] u8  @ 39845888   (4,194,304)
//  total 44,040,192 B
// ---------------------------------------------------------------------------

__device__ __forceinline__ unsigned short f2bf(float f) {
    unsigned int u = __float_as_uint(f);
    u += 0x7fffu + ((u >> 16) & 1u);
    return (unsigned short)(u >> 16);
}
__device__ __forceinline__ float b2f(unsigned short h) {
    return __uint_as_float(((unsigned int)h) << 16);
}

// ---------------------------------------------------------------------------
// Kernel 1: pack Bpt[n][k] (transposed, hi/lo bf16 split)  [unchanged]
// ---------------------------------------------------------------------------
__global__ __launch_bounds__(256) void pack_kernel(const float* __restrict__ W,
                                                   const float* __restrict__ a1,
                                                   const float* __restrict__ a2,
                                                   unsigned short* __restrict__ Bh,
                                                   unsigned short* __restrict__ Bl) {
    const int n = blockIdx.x;
    const int tid = threadIdx.x;
    if (n < 1024) {
        const int h = n >> 7, d = n & 127;
        const float* w = W + (size_t)(h * 3 + 2) * 1024 * 128 + d;
        for (int k = tid; k < 1024; k += 256) {
            float v = w[(size_t)k * 128];
            unsigned short hi = f2bf(v);
            Bh[(size_t)n * 1024 + k] = hi;
            Bl[(size_t)n * 1024 + k] = f2bf(v - b2f(hi));
        }
    } else if (n < 1072) {
        const int c = n - 1024;
        const int s = c / 24, rem = c % 24, t = rem >> 3, h = rem & 7;
        const float* a = (s ? a2 : a1) + (h * 3 + t) * 128;
        const float* wb = W + (size_t)(h * 3 + t) * 1024 * 128;
        for (int k = tid; k < 1024; k += 256) {
            const float4* wr4 = (const float4*)(wb + (size_t)k * 128);
            const float4* a4 = (const float4*)a;
            float acc = 0.f;
            #pragma unroll 8
            for (int dd = 0; dd < 32; ++dd) {
                float4 wv = wr4[dd], av = a4[dd];
                acc += wv.x * av.x + wv.y * av.y + wv.z * av.z + wv.w * av.w;
            }
            unsigned short hi = f2bf(acc);
            Bh[(size_t)n * 1024 + k] = hi;
            Bl[(size_t)n * 1024 + k] = f2bf(acc - b2f(hi));
        }
    } else {
        for (int k = tid; k < 1024; k += 256) {
            Bh[(size_t)n * 1024 + k] = 0;
            Bl[(size_t)n * 1024 + k] = 0;
        }
    }
}

// ---------------------------------------------------------------------------
// Kernel 2: bf16x3 MFMA GEMM  [unchanged — verified]
// ---------------------------------------------------------------------------
__global__ __launch_bounds__(256, 3) void mgemm(const float* __restrict__ X,
                                                const unsigned short* __restrict__ Bh,
                                                const unsigned short* __restrict__ Bl,
                                                const float* __restrict__ nm,
                                                unsigned short* __restrict__ Yh,
                                                float* __restrict__ LR) {
    __shared__ unsigned short Ah[128 * 32];
    __shared__ unsigned short Al[128 * 32];
    __shared__ unsigned short Bhs[128 * 32];
    __shared__ unsigned short Bls[128 * 32];

    const int bid = blockIdx.x;
    const int swz = (bid & 7) * 72 + (bid >> 3);
    const int nt = swz % 9, mt = swz / 9;
    const int n0 = nt * 128, m0 = mt * 128;

    const int tid = threadIdx.x;
    const int lane = tid & 63, w = tid >> 6;
    const int wr = w >> 1, wc = w & 1;
    const int fr = lane & 15, fq = lane >> 4;

    f32x4 acc[4][4];
    #pragma unroll
    for (int m = 0; m < 4; ++m)
        #pragma unroll
        for (int n = 0; n < 4; ++n) acc[m][n] = (f32x4){0.f, 0.f, 0.f, 0.f};

    const int arow = tid >> 1, ahalf = tid & 1;
    const float* xs = X + (size_t)(m0 + arow) * 1024 + ahalf * 16;
    unsigned short* adh = Ah + arow * 32 + ahalf * 16;
    unsigned short* adl = Al + arow * 32 + ahalf * 16;

    for (int k0 = 0; k0 < 1024; k0 += 32) {
        __syncthreads();

        #pragma unroll
        for (int q = 0; q < 2; ++q) {
            const int s = q * 256 + tid;
            const int brow = s >> 2, bkb = s & 3;
            const unsigned short* gh = Bh + (size_t)(n0 + brow) * 1024 + k0 + bkb * 8;
            const unsigned short* gl = Bl + (size_t)(n0 + brow) * 1024 + k0 + bkb * 8;
            unsigned short* dh = Bhs + (q * 256 + w * 64) * 8;
            unsigned short* dl = Bls + (q * 256 + w * 64) * 8;
            __builtin_amdgcn_global_load_lds(
                (const __attribute__((address_space(1))) void*)gh,
                (__attribute__((address_space(3))) void*)dh, 16, 0, 0);
            __builtin_amdgcn_global_load_lds(
                (const __attribute__((address_space(1))) void*)gl,
                (__attribute__((address_space(3))) void*)dl, 16, 0, 0);
        }

        float xf[16];
        #pragma unroll
        for (int i = 0; i < 4; ++i) {
            float4 v = *(const float4*)(xs + k0 + i * 4);
            xf[i * 4 + 0] = v.x; xf[i * 4 + 1] = v.y;
            xf[i * 4 + 2] = v.z; xf[i * 4 + 3] = v.w;
        }
        u16x8 vh0, vh1, vl0, vl1;
        #pragma unroll
        for (int i = 0; i < 8; ++i) {
            unsigned short hi = f2bf(xf[i]);
            vh0[i] = hi;
            vl0[i] = f2bf(xf[i] - b2f(hi));
        }
        #pragma unroll
        for (int i = 0; i < 8; ++i) {
            unsigned short hi = f2bf(xf[8 + i]);
            vh1[i] = hi;
            vl1[i] = f2bf(xf[8 + i] - b2f(hi));
        }
        *(u16x8*)(adh) = vh0;
        *(u16x8*)(adh + 8) = vh1;
        *(u16x8*)(adl) = vl0;
        *(u16x8*)(adl + 8) = vl1;

        __syncthreads();

        bf16x8 amh[4], bnh[4];
        #pragma unroll
        for (int m = 0; m < 4; ++m)
            amh[m] = *(bf16x8*)(Ah + (wr * 64 + m * 16 + fr) * 32 + fq * 8);
        #pragma unroll
        for (int n = 0; n < 4; ++n)
            bnh[n] = *(bf16x8*)(Bhs + (wc * 64 + n * 16 + fr) * 32 + fq * 8);
        #pragma unroll
        for (int m = 0; m < 4; ++m)
            #pragma unroll
            for (int n = 0; n < 4; ++n)
                acc[m][n] = __builtin_amdgcn_mfma_f32_16x16x32_bf16(amh[m], bnh[n], acc[m][n], 0, 0, 0);

        bf16x8 bnl[4];
        #pragma unroll
        for (int n = 0; n < 4; ++n)
            bnl[n] = *(bf16x8*)(Bls + (wc * 64 + n * 16 + fr) * 32 + fq * 8);
        #pragma unroll
        for (int m = 0; m < 4; ++m)
            #pragma unroll
            for (int n = 0; n < 4; ++n)
                acc[m][n] = __builtin_amdgcn_mfma_f32_16x16x32_bf16(amh[m], bnl[n], acc[m][n], 0, 0, 0);

        bf16x8 aml[4];
        #pragma unroll
        for (int m = 0; m < 4; ++m)
            aml[m] = *(bf16x8*)(Al + (wr * 64 + m * 16 + fr) * 32 + fq * 8);
        #pragma unroll
        for (int m = 0; m < 4; ++m)
            #pragma unroll
            for (int n = 0; n < 4; ++n)
                acc[m][n] = __builtin_amdgcn_mfma_f32_16x16x32_bf16(aml[m], bnh[n], acc[m][n], 0, 0, 0);
    }

    #pragma unroll
    for (int m = 0; m < 4; ++m) {
        #pragma unroll
        for (int r = 0; r < 4; ++r) {
            const int R = m0 + wr * 64 + m * 16 + fq * 4 + r;
            const float mk = nm[R];
            #pragma unroll
            for (int n = 0; n < 4; ++n) {
                const int col = n0 + wc * 64 + n * 16 + fr;
                const float v = acc[m][n][r];
                if (col < 1024) {
                    Yh[(size_t)R * 1024 + col] = f2bf(v * mk);
                } else {
                    const int c = col - 1024;
                    if (c < 48) LR[(size_t)c * 8192 + R] = v;
                }
            }
        }
    }
}

// ---------------------------------------------------------------------------
// Kernel 3: transpose Yh -> Vt[h][b][d][j]  [unchanged]
// ---------------------------------------------------------------------------
__global__ __launch_bounds__(256) void vt_kernel(const unsigned short* __restrict__ Yh,
                                                 unsigned short* __restrict__ Vt) {
    __shared__ __align__(16) unsigned short tile[64 * 136];
    const int bid = blockIdx.x;
    const int jt = bid & 7, b = (bid >> 3) & 15, h = bid >> 7;
    const int j0 = jt * 64;
    const int tid = threadIdx.x;

    #pragma unroll
    for (int rep = 0; rep < 4; ++rep) {
        int idx = rep * 256 + tid;
        int j = idx >> 4, dc = (idx & 15) * 8;
        u16x8 v = *(const u16x8*)(Yh + (size_t)(b * 512 + j0 + j) * 1024 + h * 128 + dc);
        *(u16x8*)(tile + j * 136 + dc) = v;
    }
    __syncthreads();
    #pragma unroll
    for (int rep = 0; rep < 4; ++rep) {
        int idx = rep * 256 + tid;
        int d = idx >> 3, jc = (idx & 7) * 8;
        u16x8 o;
        #pragma unroll
        for (int q = 0; q < 8; ++q) o[q] = tile[(jc + q) * 136 + d];
        *(u16x8*)(Vt + ((size_t)(h * 16 + b) * 128 + d) * 512 + j0 + jc) = o;
    }
}

// ---------------------------------------------------------------------------
// Kernel 3b: adj int32 -> byte array adjB  [unchanged]
// ---------------------------------------------------------------------------
__global__ __launch_bounds__(256) void adjb_kernel(const int* __restrict__ adj,
                                                   unsigned char* __restrict__ adjB) {
    const int idx = blockIdx.x * 256 + threadIdx.x;
    const int4* s = (const int4*)(adj + (size_t)idx * 16);
    int4 v0 = s[0], v1 = s[1], v2 = s[2], v3 = s[3];
    union { unsigned char c[16]; int4 v; } o;
    o.c[0] = (unsigned char)v0.x; o.c[1] = (unsigned char)v0.y;
    o.c[2] = (unsigned char)v0.z; o.c[3] = (unsigned char)v0.w;
    o.c[4] = (unsigned char)v1.x; o.c[5] = (unsigned char)v1.y;
    o.c[6] = (unsigned char)v1.z; o.c[7] = (unsigned char)v1.w;
    o.c[8] = (unsigned char)v2.x; o.c[9] = (unsigned char)v2.y;
    o.c[10] = (unsigned char)v2.z; o.c[11] = (unsigned char)v2.w;
    o.c[12] = (unsigned char)v3.x; o.c[13] = (unsigned char)v3.y;
    o.c[14] = (unsigned char)v3.z; o.c[15] = (unsigned char)v3.w;
    *(int4*)(adjB + (size_t)idx * 16) = o.v;
}

// ---------------------------------------------------------------------------
// Kernel 4: fused attn, j-split across wave pairs (256-thr blocks, no spill).
//   grid 2048: itg2 = bid>>7 (0..15) -> i-tiles itg2*2 + {0,1}; hb = bid&127.
//   Wave w: i-tile (w&1), j-half (w>>1). 8192 wave-tasks = 32 waves/CU grid.
//   __launch_bounds__(256,8): 8 blocks/CU, VGPR cap 64 (body measured 56).
//   Upper j-half waves deposit acc+rsum in LDS (16.5 KB); one barrier;
//   lower waves combine + normalize + write.
// ---------------------------------------------------------------------------
__global__ __launch_bounds__(256, 8) void attn_kernel(const unsigned short* __restrict__ Vt,
                                                      const float* __restrict__ LR,
                                                      const unsigned char* __restrict__ adjB,
                                                      float* __restrict__ out) {
    __shared__ f32x4 accL[16][64];   // [wl*8+n][lane]
    __shared__ float rsL[2][64];

    const int bid = blockIdx.x;
    const int itg2 = bid >> 7, hb = bid & 127, h = hb >> 4, b = hb & 15;
    const int tid = threadIdx.x, w = tid >> 6, lane = tid & 63;
    const int fr = lane & 15, fq = lane >> 4;
    const int wl = w & 1, jh = w >> 1;
    const int i0 = (itg2 * 2 + wl) * 16;
    const int jb = jh * 256 + fq * 8;

    const float* R0 = LR + (size_t)(24 + h) * 8192 + b * 512;
    const float* R1 = LR + (size_t)(32 + h) * 8192 + b * 512;
    const float* R2 = LR + (size_t)(40 + h) * 8192 + b * 512;
    const float lf0 = LR[(size_t)(h) * 8192 + b * 512 + i0 + fr];
    const float lf1 = LR[(size_t)(8 + h) * 8192 + b * 512 + i0 + fr];
    const float lf2 = LR[(size_t)(16 + h) * 8192 + b * 512 + i0 + fr];
    const unsigned char* arow = adjB + (size_t)(b * 512 + i0 + fr) * 512;
    const unsigned short* vt = Vt + (size_t)(h * 16 + b) * 128 * 512;

    f32x4 acc[8];
    #pragma unroll
    for (int n = 0; n < 8; ++n) acc[n] = (f32x4){0.f, 0.f, 0.f, 0.f};
    float rsum = 0.f;

    #pragma unroll 1
    for (int os = 0; os < 4; ++os) {
        const int jA = jb + os * 64;        // substep A cols
        const int jB = jA + 32;             // substep B cols

        uint2 aA = *(const uint2*)(arow + jA);
        uint2 aB = *(const uint2*)(arow + jB);
        float4 f0Aa = *(const float4*)(R0 + jA), f0Ab = *(const float4*)(R0 + jA + 4);
        float4 f1Aa = *(const float4*)(R1 + jA), f1Ab = *(const float4*)(R1 + jA + 4);
        float4 f2Aa = *(const float4*)(R2 + jA), f2Ab = *(const float4*)(R2 + jA + 4);
        float4 f0Ba = *(const float4*)(R0 + jB), f0Bb = *(const float4*)(R0 + jB + 4);
        float4 f1Ba = *(const float4*)(R1 + jB), f1Bb = *(const float4*)(R1 + jB + 4);
        float4 f2Ba = *(const float4*)(R2 + jB), f2Bb = *(const float4*)(R2 + jB + 4);

        u16x8 vhA, vlA, vhB, vlB;
        {
            float e0[8] = {f0Aa.x, f0Aa.y, f0Aa.z, f0Aa.w, f0Ab.x, f0Ab.y, f0Ab.z, f0Ab.w};
            float e1[8] = {f1Aa.x, f1Aa.y, f1Aa.z, f1Aa.w, f1Ab.x, f1Ab.y, f1Ab.z, f1Ab.w};
            float e2[8] = {f2Aa.x, f2Aa.y, f2Aa.z, f2Aa.w, f2Ab.x, f2Ab.y, f2Ab.z, f2Ab.w};
            #pragma unroll
            for (int q = 0; q < 8; ++q) {
                unsigned av = ((q < 4 ? aA.x : aA.y) >> (8 * (q & 3))) & 255u;
                float sb = (av == 1u) ? (lf0 + e0[q])
                         : (av == 2u) ? (lf1 + e1[q]) : (lf2 + e2[q]);
                float sv = fmaxf(sb, 0.f) + 0.2f * fminf(sb, 0.f);
                float p = (av != 0u) ? __expf(sv) : 0.f;
                rsum += p;
                unsigned short hi = f2bf(p);
                vhA[q] = hi;
                vlA[q] = f2bf(p - b2f(hi));
            }
        }
        {
            float e0[8] = {f0Ba.x, f0Ba.y, f0Ba.z, f0Ba.w, f0Bb.x, f0Bb.y, f0Bb.z, f0Bb.w};
            float e1[8] = {f1Ba.x, f1Ba.y, f1Ba.z, f1Ba.w, f1Bb.x, f1Bb.y, f1Bb.z, f1Bb.w};
            float e2[8] = {f2Ba.x, f2Ba.y, f2Ba.z, f2Ba.w, f2Bb.x, f2Bb.y, f2Bb.z, f2Bb.w};
            #pragma unroll
            for (int q = 0; q < 8; ++q) {
                unsigned av = ((q < 4 ? aB.x : aB.y) >> (8 * (q & 3))) & 255u;
                float sb = (av == 1u) ? (lf0 + e0[q])
                         : (av == 2u) ? (lf1 + e1[q]) : (lf2 + e2[q]);
                float sv = fmaxf(sb, 0.f) + 0.2f * fminf(sb, 0.f);
                float p = (av != 0u) ? __expf(sv) : 0.f;
                rsum += p;
                unsigned short hi = f2bf(p);
                vhB[q] = hi;
                vlB[q] = f2bf(p - b2f(hi));
            }
        }
        bf16x8 ahA = *(bf16x8*)&vhA, alA = *(bf16x8*)&vlA;
        bf16x8 ahB = *(bf16x8*)&vhB, alB = *(bf16x8*)&vlB;

        #pragma unroll
        for (int n = 0; n < 8; ++n) {
            const unsigned short* vr = vt + (size_t)(n * 16 + fr) * 512 + jA;
            bf16x8 vbA = *(const bf16x8*)(vr);
            bf16x8 vbB = *(const bf16x8*)(vr + 32);
            acc[n] = __builtin_amdgcn_mfma_f32_16x16x32_bf16(ahA, vbA, acc[n], 0, 0, 0);
            acc[n] = __builtin_amdgcn_mfma_f32_16x16x32_bf16(alA, vbA, acc[n], 0, 0, 0);
            acc[n] = __builtin_amdgcn_mfma_f32_16x16x32_bf16(ahB, vbB, acc[n], 0, 0, 0);
            acc[n] = __builtin_amdgcn_mfma_f32_16x16x32_bf16(alB, vbB, acc[n], 0, 0, 0);
        }
    }

    // ---- cross-wave combine: upper j-half waves deposit, lower combine
    if (jh == 1) {
        #pragma unroll
        for (int n = 0; n < 8; ++n) accL[wl * 8 + n][lane] = acc[n];
        rsL[wl][lane] = rsum;
    }
    __syncthreads();
    if (jh == 0) {
        #pragma unroll
        for (int n = 0; n < 8; ++n) {
            f32x4 p = accL[wl * 8 + n][lane];
            acc[n][0] += p[0]; acc[n][1] += p[1];
            acc[n][2] += p[2]; acc[n][3] += p[3];
        }
        rsum += rsL[wl][lane];

        rsum += __shfl_xor(rsum, 16);
        rsum += __shfl_xor(rsum, 32);

        #pragma unroll
        for (int rr = 0; rr < 4; ++rr) {
            const int row = fq * 4 + rr;
            const float inv = 1.0f / __shfl(rsum, row);
            #pragma unroll
            for (int n = 0; n < 8; ++n) {
                out[(size_t)(b * 512 + i0 + row) * 1024 + h * 128 + n * 16 + fr] =
                    fmaxf(acc[n][rr] * inv, 0.f);
            }
        }
    }
}

// ---------------------------------------------------------------------------
extern "C" void kernel_launch(void* const* d_in, const int* in_sizes, int n_in,
                              void* d_out, int out_size, void* d_ws, size_t ws_size,
                              hipStream_t stream) {
    const float* x   = (const float*)d_in[0];
    const int*   adj = (const int*)d_in[1];
    const float* nm  = (const float*)d_in[2];
    const float* W   = (const float*)d_in[3];
    const float* a1  = (const float*)d_in[4];
    const float* a2  = (const float*)d_in[5];
    float* out = (float*)d_out;
    char* wsb = (char*)d_ws;

    unsigned short* Bh   = (unsigned short*)(wsb);
    unsigned short* Bl   = (unsigned short*)(wsb + 2359296);
    unsigned short* Yh   = (unsigned short*)(wsb + 4718592);
    float*          LR   = (float*)(wsb + 21495808);
    unsigned short* Vt   = (unsigned short*)(wsb + 23068672);
    unsigned char*  adjB = (unsigned char*)(wsb + 39845888);

    hipLaunchKernelGGL(adjb_kernel, dim3(1024), dim3(256), 0, stream, adj, adjB);
    hipLaunchKernelGGL(pack_kernel, dim3(1152), dim3(256), 0, stream, W, a1, a2, Bh, Bl);
    hipLaunchKernelGGL(mgemm, dim3(576), dim3(256), 0, stream, x, Bh, Bl, nm, Yh, LR);
    hipLaunchKernelGGL(vt_kernel, dim3(1024), dim3(256), 0, stream, Yh, Vt);
    hipLaunchKernelGGL(attn_kernel, dim3(2048), dim3(256), 0, stream, Vt, LR, adjB, out);
}

// Round 10
// 165.007 us; speedup vs baseline: 1.6475x; 1.6475x over previous
//
#include <hip/hip_runtime.h>

typedef __attribute__((ext_vector_type(8))) __bf16 bf16x8;
typedef __attribute__((ext_vector_type(8))) unsigned short u16x8;
typedef __attribute__((ext_vector_type(4))) float f32x4;

#define NEGV (-1e30f)

// ---------------------------------------------------------------------------
// Workspace layout (bytes):
//  Bh  : [1152][1024] bf16  @ 0          (2,359,296)
//  Bl  : [1152][1024] bf16  @ 2359296    (2,359,296)
//  Yh  : [8192][1024] bf16  @ 4718592    (16,777,216)  h_last * node_mask
//  LR  : [48][8192]  f32    @ 21495808   (1,572,864)   left/right, c = s*24+t*8+h
//  Vt  : [8][16][128][512] bf16 @ 23068672 (16,777,216) transposed h_last
//  adjB: [16][512][512] u8  @ 39845888   (4,194,304)
//  total 44,040,192 B
// ---------------------------------------------------------------------------

__device__ __forceinline__ unsigned short f2bf(float f) {
    unsigned int u = __float_as_uint(f);
    u += 0x7fffu + ((u >> 16) & 1u);
    return (unsigned short)(u >> 16);
}
__device__ __forceinline__ float b2f(unsigned short h) {
    return __uint_as_float(((unsigned int)h) << 16);
}

// ---------------------------------------------------------------------------
// Kernel 1: pack Bpt[n][k] (transposed, hi/lo bf16 split)  [unchanged]
// ---------------------------------------------------------------------------
__global__ __launch_bounds__(256) void pack_kernel(const float* __restrict__ W,
                                                   const float* __restrict__ a1,
                                                   const float* __restrict__ a2,
                                                   unsigned short* __restrict__ Bh,
                                                   unsigned short* __restrict__ Bl) {
    const int n = blockIdx.x;
    const int tid = threadIdx.x;
    if (n < 1024) {
        const int h = n >> 7, d = n & 127;
        const float* w = W + (size_t)(h * 3 + 2) * 1024 * 128 + d;
        for (int k = tid; k < 1024; k += 256) {
            float v = w[(size_t)k * 128];
            unsigned short hi = f2bf(v);
            Bh[(size_t)n * 1024 + k] = hi;
            Bl[(size_t)n * 1024 + k] = f2bf(v - b2f(hi));
        }
    } else if (n < 1072) {
        const int c = n - 1024;
        const int s = c / 24, rem = c % 24, t = rem >> 3, h = rem & 7;
        const float* a = (s ? a2 : a1) + (h * 3 + t) * 128;
        const float* wb = W + (size_t)(h * 3 + t) * 1024 * 128;
        for (int k = tid; k < 1024; k += 256) {
            const float4* wr4 = (const float4*)(wb + (size_t)k * 128);
            const float4* a4 = (const float4*)a;
            float acc = 0.f;
            #pragma unroll 8
            for (int dd = 0; dd < 32; ++dd) {
                float4 wv = wr4[dd], av = a4[dd];
                acc += wv.x * av.x + wv.y * av.y + wv.z * av.z + wv.w * av.w;
            }
            unsigned short hi = f2bf(acc);
            Bh[(size_t)n * 1024 + k] = hi;
            Bl[(size_t)n * 1024 + k] = f2bf(acc - b2f(hi));
        }
    } else {
        for (int k = tid; k < 1024; k += 256) {
            Bh[(size_t)n * 1024 + k] = 0;
            Bl[(size_t)n * 1024 + k] = 0;
        }
    }
}

// ---------------------------------------------------------------------------
// Kernel 2: bf16x3 MFMA GEMM  [unchanged — verified]
// ---------------------------------------------------------------------------
__global__ __launch_bounds__(256, 3) void mgemm(const float* __restrict__ X,
                                                const unsigned short* __restrict__ Bh,
                                                const unsigned short* __restrict__ Bl,
                                                const float* __restrict__ nm,
                                                unsigned short* __restrict__ Yh,
                                                float* __restrict__ LR) {
    __shared__ unsigned short Ah[128 * 32];
    __shared__ unsigned short Al[128 * 32];
    __shared__ unsigned short Bhs[128 * 32];
    __shared__ unsigned short Bls[128 * 32];

    const int bid = blockIdx.x;
    const int swz = (bid & 7) * 72 + (bid >> 3);
    const int nt = swz % 9, mt = swz / 9;
    const int n0 = nt * 128, m0 = mt * 128;

    const int tid = threadIdx.x;
    const int lane = tid & 63, w = tid >> 6;
    const int wr = w >> 1, wc = w & 1;
    const int fr = lane & 15, fq = lane >> 4;

    f32x4 acc[4][4];
    #pragma unroll
    for (int m = 0; m < 4; ++m)
        #pragma unroll
        for (int n = 0; n < 4; ++n) acc[m][n] = (f32x4){0.f, 0.f, 0.f, 0.f};

    const int arow = tid >> 1, ahalf = tid & 1;
    const float* xs = X + (size_t)(m0 + arow) * 1024 + ahalf * 16;
    unsigned short* adh = Ah + arow * 32 + ahalf * 16;
    unsigned short* adl = Al + arow * 32 + ahalf * 16;

    for (int k0 = 0; k0 < 1024; k0 += 32) {
        __syncthreads();

        #pragma unroll
        for (int q = 0; q < 2; ++q) {
            const int s = q * 256 + tid;
            const int brow = s >> 2, bkb = s & 3;
            const unsigned short* gh = Bh + (size_t)(n0 + brow) * 1024 + k0 + bkb * 8;
            const unsigned short* gl = Bl + (size_t)(n0 + brow) * 1024 + k0 + bkb * 8;
            unsigned short* dh = Bhs + (q * 256 + w * 64) * 8;
            unsigned short* dl = Bls + (q * 256 + w * 64) * 8;
            __builtin_amdgcn_global_load_lds(
                (const __attribute__((address_space(1))) void*)gh,
                (__attribute__((address_space(3))) void*)dh, 16, 0, 0);
            __builtin_amdgcn_global_load_lds(
                (const __attribute__((address_space(1))) void*)gl,
                (__attribute__((address_space(3))) void*)dl, 16, 0, 0);
        }

        float xf[16];
        #pragma unroll
        for (int i = 0; i < 4; ++i) {
            float4 v = *(const float4*)(xs + k0 + i * 4);
            xf[i * 4 + 0] = v.x; xf[i * 4 + 1] = v.y;
            xf[i * 4 + 2] = v.z; xf[i * 4 + 3] = v.w;
        }
        u16x8 vh0, vh1, vl0, vl1;
        #pragma unroll
        for (int i = 0; i < 8; ++i) {
            unsigned short hi = f2bf(xf[i]);
            vh0[i] = hi;
            vl0[i] = f2bf(xf[i] - b2f(hi));
        }
        #pragma unroll
        for (int i = 0; i < 8; ++i) {
            unsigned short hi = f2bf(xf[8 + i]);
            vh1[i] = hi;
            vl1[i] = f2bf(xf[8 + i] - b2f(hi));
        }
        *(u16x8*)(adh) = vh0;
        *(u16x8*)(adh + 8) = vh1;
        *(u16x8*)(adl) = vl0;
        *(u16x8*)(adl + 8) = vl1;

        __syncthreads();

        bf16x8 amh[4], bnh[4];
        #pragma unroll
        for (int m = 0; m < 4; ++m)
            amh[m] = *(bf16x8*)(Ah + (wr * 64 + m * 16 + fr) * 32 + fq * 8);
        #pragma unroll
        for (int n = 0; n < 4; ++n)
            bnh[n] = *(bf16x8*)(Bhs + (wc * 64 + n * 16 + fr) * 32 + fq * 8);
        #pragma unroll
        for (int m = 0; m < 4; ++m)
            #pragma unroll
            for (int n = 0; n < 4; ++n)
                acc[m][n] = __builtin_amdgcn_mfma_f32_16x16x32_bf16(amh[m], bnh[n], acc[m][n], 0, 0, 0);

        bf16x8 bnl[4];
        #pragma unroll
        for (int n = 0; n < 4; ++n)
            bnl[n] = *(bf16x8*)(Bls + (wc * 64 + n * 16 + fr) * 32 + fq * 8);
        #pragma unroll
        for (int m = 0; m < 4; ++m)
            #pragma unroll
            for (int n = 0; n < 4; ++n)
                acc[m][n] = __builtin_amdgcn_mfma_f32_16x16x32_bf16(amh[m], bnl[n], acc[m][n], 0, 0, 0);

        bf16x8 aml[4];
        #pragma unroll
        for (int m = 0; m < 4; ++m)
            aml[m] = *(bf16x8*)(Al + (wr * 64 + m * 16 + fr) * 32 + fq * 8);
        #pragma unroll
        for (int m = 0; m < 4; ++m)
            #pragma unroll
            for (int n = 0; n < 4; ++n)
                acc[m][n] = __builtin_amdgcn_mfma_f32_16x16x32_bf16(aml[m], bnh[n], acc[m][n], 0, 0, 0);
    }

    #pragma unroll
    for (int m = 0; m < 4; ++m) {
        #pragma unroll
        for (int r = 0; r < 4; ++r) {
            const int R = m0 + wr * 64 + m * 16 + fq * 4 + r;
            const float mk = nm[R];
            #pragma unroll
            for (int n = 0; n < 4; ++n) {
                const int col = n0 + wc * 64 + n * 16 + fr;
                const float v = acc[m][n][r];
                if (col < 1024) {
                    Yh[(size_t)R * 1024 + col] = f2bf(v * mk);
                } else {
                    const int c = col - 1024;
                    if (c < 48) LR[(size_t)c * 8192 + R] = v;
                }
            }
        }
    }
}

// ---------------------------------------------------------------------------
// Kernel 3: transpose Yh -> Vt[h][b][d][j]  [unchanged]
// ---------------------------------------------------------------------------
__global__ __launch_bounds__(256) void vt_kernel(const unsigned short* __restrict__ Yh,
                                                 unsigned short* __restrict__ Vt) {
    __shared__ __align__(16) unsigned short tile[64 * 136];
    const int bid = blockIdx.x;
    const int jt = bid & 7, b = (bid >> 3) & 15, h = bid >> 7;
    const int j0 = jt * 64;
    const int tid = threadIdx.x;

    #pragma unroll
    for (int rep = 0; rep < 4; ++rep) {
        int idx = rep * 256 + tid;
        int j = idx >> 4, dc = (idx & 15) * 8;
        u16x8 v = *(const u16x8*)(Yh + (size_t)(b * 512 + j0 + j) * 1024 + h * 128 + dc);
        *(u16x8*)(tile + j * 136 + dc) = v;
    }
    __syncthreads();
    #pragma unroll
    for (int rep = 0; rep < 4; ++rep) {
        int idx = rep * 256 + tid;
        int d = idx >> 3, jc = (idx & 7) * 8;
        u16x8 o;
        #pragma unroll
        for (int q = 0; q < 8; ++q) o[q] = tile[(jc + q) * 136 + d];
        *(u16x8*)(Vt + ((size_t)(h * 16 + b) * 128 + d) * 512 + j0 + jc) = o;
    }
}

// ---------------------------------------------------------------------------
// Kernel 3b: adj int32 -> byte array adjB  [unchanged]
// ---------------------------------------------------------------------------
__global__ __launch_bounds__(256) void adjb_kernel(const int* __restrict__ adj,
                                                   unsigned char* __restrict__ adjB) {
    const int idx = blockIdx.x * 256 + threadIdx.x;
    const int4* s = (const int4*)(adj + (size_t)idx * 16);
    int4 v0 = s[0], v1 = s[1], v2 = s[2], v3 = s[3];
    union { unsigned char c[16]; int4 v; } o;
    o.c[0] = (unsigned char)v0.x; o.c[1] = (unsigned char)v0.y;
    o.c[2] = (unsigned char)v0.z; o.c[3] = (unsigned char)v0.w;
    o.c[4] = (unsigned char)v1.x; o.c[5] = (unsigned char)v1.y;
    o.c[6] = (unsigned char)v1.z; o.c[7] = (unsigned char)v1.w;
    o.c[8] = (unsigned char)v2.x; o.c[9] = (unsigned char)v2.y;
    o.c[10] = (unsigned char)v2.z; o.c[11] = (unsigned char)v2.w;
    o.c[12] = (unsigned char)v3.x; o.c[13] = (unsigned char)v3.y;
    o.c[14] = (unsigned char)v3.z; o.c[15] = (unsigned char)v3.w;
    *(int4*)(adjB + (size_t)idx * 16) = o.v;
}

// ---------------------------------------------------------------------------
// Kernel 4: fused attn = round-7 decomposition + LDS pipeline.
//   grid 1024, 256 thr (4 waves = 4 i-tiles of one (h,b)); per os step (64 j):
//   V panel (16KB) staged into LDS in MFMA-FRAGMENT ORDER via global_load_lds
//   (double-buffered, issued one step ahead -> latency hidden under compute);
//   frag reads are consecutive-lane ds_read_b128 (conflict-free). R staged in
//   LDS once (broadcast reads). adjB register-prefetched one step ahead.
//   LDS 39KB -> 4 blocks/CU. launch_bounds(256,4): cap 128 regs (~110 used).
// ---------------------------------------------------------------------------
__global__ __launch_bounds__(256, 4) void attn_kernel(const unsigned short* __restrict__ Vt,
                                                      const float* __restrict__ LR,
                                                      const unsigned char* __restrict__ adjB,
                                                      float* __restrict__ out) {
    __shared__ __align__(16) unsigned short Vb[2][16 * 512];  // fragment-ordered panels
    __shared__ __align__(16) float rt[3 * 512];

    const int bid = blockIdx.x;
    const int itg = bid >> 7, hb = bid & 127, h = hb >> 4, b = hb & 15;
    const int tid = threadIdx.x, w = tid >> 6, lane = tid & 63;
    const int fr = lane & 15, fq = lane >> 4;
    const int i0 = (itg * 4 + w) * 16;
    const int fq8 = fq * 8;

    // ---- stage R (3x512 f32) into LDS once
    for (int idx = tid; idx < 1536; idx += 256) {
        int t = idx >> 9, j = idx & 511;
        rt[idx] = LR[(size_t)(24 + t * 8 + h) * 8192 + b * 512 + j];
    }
    const float lf0 = LR[(size_t)(h) * 8192 + b * 512 + i0 + fr];
    const float lf1 = LR[(size_t)(8 + h) * 8192 + b * 512 + i0 + fr];
    const float lf2 = LR[(size_t)(16 + h) * 8192 + b * 512 + i0 + fr];
    const unsigned char* arow = adjB + (size_t)(b * 512 + i0 + fr) * 512;
    const unsigned short* vt = Vt + (size_t)(h * 16 + b) * 128 * 512;

    // V panel stage: wave w stages nh = q*4+w (q=0..3); 1KB per gload_lds.
    // src lane elem: (n*16+fr)*512 + os*64 + hf*32 + fq*8  (n=nh>>1, hf=nh&1)
    // dest (wave-uniform base): nh*512 u16; +lane*16B implicit.
#define STAGE_V(bufp, os_) do {                                                   \
        _Pragma("unroll")                                                          \
        for (int q_ = 0; q_ < 4; ++q_) {                                           \
            const int nh_ = q_ * 4 + w;                                            \
            const unsigned short* src_ = vt + (size_t)((nh_ >> 1) * 16 + fr) * 512 \
                                          + (os_) * 64 + (nh_ & 1) * 32 + fq8;     \
            unsigned short* dst_ = (bufp) + nh_ * 512;                             \
            __builtin_amdgcn_global_load_lds(                                      \
                (const __attribute__((address_space(1))) void*)src_,               \
                (__attribute__((address_space(3))) void*)dst_, 16, 0, 0);          \
        }                                                                          \
    } while (0)

    STAGE_V(&Vb[0][0], 0);
    uint2 aA = *(const uint2*)(arow + fq8);
    uint2 aB = *(const uint2*)(arow + fq8 + 32);

    f32x4 acc[8];
    #pragma unroll
    for (int n = 0; n < 8; ++n) acc[n] = (f32x4){0.f, 0.f, 0.f, 0.f};
    float rsum = 0.f;

    __syncthreads();   // panel 0 + rt ready

    #pragma unroll 1
    for (int os = 0; os < 8; ++os) {
        unsigned short* vb = &Vb[os & 1][0];
        if (os < 7) STAGE_V(&Vb[(os & 1) ^ 1][0], os + 1);   // async prefetch

        const int jA = os * 64 + fq8;
        const int jB = jA + 32;

        // scores substep A (R from LDS, broadcast within fq group)
        u16x8 vhA, vlA, vhB, vlB;
        {
            float4 r0a = *(const float4*)(rt + jA), r0b = *(const float4*)(rt + jA + 4);
            float4 r1a = *(const float4*)(rt + 512 + jA), r1b = *(const float4*)(rt + 512 + jA + 4);
            float4 r2a = *(const float4*)(rt + 1024 + jA), r2b = *(const float4*)(rt + 1024 + jA + 4);
            float e0[8] = {r0a.x, r0a.y, r0a.z, r0a.w, r0b.x, r0b.y, r0b.z, r0b.w};
            float e1[8] = {r1a.x, r1a.y, r1a.z, r1a.w, r1b.x, r1b.y, r1b.z, r1b.w};
            float e2[8] = {r2a.x, r2a.y, r2a.z, r2a.w, r2b.x, r2b.y, r2b.z, r2b.w};
            #pragma unroll
            for (int q = 0; q < 8; ++q) {
                unsigned av = ((q < 4 ? aA.x : aA.y) >> (8 * (q & 3))) & 255u;
                float sb = (av == 1u) ? (lf0 + e0[q])
                         : (av == 2u) ? (lf1 + e1[q]) : (lf2 + e2[q]);
                float sv = fmaxf(sb, 0.f) + 0.2f * fminf(sb, 0.f);
                float p = (av != 0u) ? __expf(sv) : 0.f;
                rsum += p;
                unsigned short hi = f2bf(p);
                vhA[q] = hi;
                vlA[q] = f2bf(p - b2f(hi));
            }
        }
        // scores substep B
        {
            float4 r0a = *(const float4*)(rt + jB), r0b = *(const float4*)(rt + jB + 4);
            float4 r1a = *(const float4*)(rt + 512 + jB), r1b = *(const float4*)(rt + 512 + jB + 4);
            float4 r2a = *(const float4*)(rt + 1024 + jB), r2b = *(const float4*)(rt + 1024 + jB + 4);
            float e0[8] = {r0a.x, r0a.y, r0a.z, r0a.w, r0b.x, r0b.y, r0b.z, r0b.w};
            float e1[8] = {r1a.x, r1a.y, r1a.z, r1a.w, r1b.x, r1b.y, r1b.z, r1b.w};
            float e2[8] = {r2a.x, r2a.y, r2a.z, r2a.w, r2b.x, r2b.y, r2b.z, r2b.w};
            #pragma unroll
            for (int q = 0; q < 8; ++q) {
                unsigned av = ((q < 4 ? aB.x : aB.y) >> (8 * (q & 3))) & 255u;
                float sb = (av == 1u) ? (lf0 + e0[q])
                         : (av == 2u) ? (lf1 + e1[q]) : (lf2 + e2[q]);
                float sv = fmaxf(sb, 0.f) + 0.2f * fminf(sb, 0.f);
                float p = (av != 0u) ? __expf(sv) : 0.f;
                rsum += p;
                unsigned short hi = f2bf(p);
                vhB[q] = hi;
                vlB[q] = f2bf(p - b2f(hi));
            }
        }
        // prefetch adj for next step (regs dead after score phase)
        if (os < 7) {
            aA = *(const uint2*)(arow + (os + 1) * 64 + fq8);
            aB = *(const uint2*)(arow + (os + 1) * 64 + fq8 + 32);
        }

        bf16x8 ahA = *(bf16x8*)&vhA, alA = *(bf16x8*)&vlA;
        bf16x8 ahB = *(bf16x8*)&vhB, alB = *(bf16x8*)&vlB;

        // PV: V frags from LDS (consecutive-lane b128, conflict-free)
        #pragma unroll
        for (int n = 0; n < 8; ++n) {
            bf16x8 vA = *(bf16x8*)(vb + (n * 2 + 0) * 512 + lane * 8);
            bf16x8 vB = *(bf16x8*)(vb + (n * 2 + 1) * 512 + lane * 8);
            acc[n] = __builtin_amdgcn_mfma_f32_16x16x32_bf16(ahA, vA, acc[n], 0, 0, 0);
            acc[n] = __builtin_amdgcn_mfma_f32_16x16x32_bf16(alA, vA, acc[n], 0, 0, 0);
            acc[n] = __builtin_amdgcn_mfma_f32_16x16x32_bf16(ahB, vB, acc[n], 0, 0, 0);
            acc[n] = __builtin_amdgcn_mfma_f32_16x16x32_bf16(alB, vB, acc[n], 0, 0, 0);
        }
        __syncthreads();   // drains prefetch (ready for os+1); protects dbuf swap
    }
#undef STAGE_V

    // full row sums: partials live in the 4 fq-lanes of each fr
    rsum += __shfl_xor(rsum, 16);
    rsum += __shfl_xor(rsum, 32);

    // epilogue: C/D layout col=fr, row=fq*4+rr; rs for 'row' lives in lane 'row'
    #pragma unroll
    for (int rr = 0; rr < 4; ++rr) {
        const int row = fq * 4 + rr;
        const float inv = 1.0f / __shfl(rsum, row);
        #pragma unroll
        for (int n = 0; n < 8; ++n) {
            out[(size_t)(b * 512 + i0 + row) * 1024 + h * 128 + n * 16 + fr] =
                fmaxf(acc[n][rr] * inv, 0.f);
        }
    }
}

// ---------------------------------------------------------------------------
extern "C" void kernel_launch(void* const* d_in, const int* in_sizes, int n_in,
                              void* d_out, int out_size, void* d_ws, size_t ws_size,
                              hipStream_t stream) {
    const float* x   = (const float*)d_in[0];
    const int*   adj = (const int*)d_in[1];
    const float* nm  = (const float*)d_in[2];
    const float* W   = (const float*)d_in[3];
    const float* a1  = (const float*)d_in[4];
    const float* a2  = (const float*)d_in[5];
    float* out = (float*)d_out;
    char* wsb = (char*)d_ws;

    unsigned short* Bh   = (unsigned short*)(wsb);
    unsigned short* Bl   = (unsigned short*)(wsb + 2359296);
    unsigned short* Yh   = (unsigned short*)(wsb + 4718592);
    float*          LR   = (float*)(wsb + 21495808);
    unsigned short* Vt   = (unsigned short*)(wsb + 23068672);
    unsigned char*  adjB = (unsigned char*)(wsb + 39845888);

    hipLaunchKernelGGL(adjb_kernel, dim3(1024), dim3(256), 0, stream, adj, adjB);
    hipLaunchKernelGGL(pack_kernel, dim3(1152), dim3(256), 0, stream, W, a1, a2, Bh, Bl);
    hipLaunchKernelGGL(mgemm, dim3(576), dim3(256), 0, stream, x, Bh, Bl, nm, Yh, LR);
    hipLaunchKernelGGL(vt_kernel, dim3(1024), dim3(256), 0, stream, Yh, Vt);
    hipLaunchKernelGGL(attn_kernel, dim3(1024), dim3(256), 0, stream, Vt, LR, adjB, out);
}